// Round 2
// baseline (420.120 us; speedup 1.0000x reference)
//
#include <hip/hip_runtime.h>

// nnmodel_35708358099045 R5: LDS-free, barrier-free, pure-register kernel.
// Post-mortem of R4: occupancy stuck at 11% (3.6 resident waves/CU) despite
// 12 theoretical; per-wave lifetime ~43K cycles => serial chain of exposed
// memory waits (global->vmcnt->ds_write->lgkm->ds_read per phase) + late
// z/y load issue from register pressure. LDS staging was only there for
// coalescing, but every row is lane-private and 16B-aligned:
//   x row 10xfloat4, z row 20xfloat4, y row 10xfloat4, out row 10xfloat4.
// Scattered per-lane float4 access costs ~64 line-requests/instr but every
// line is fully consumed by the same wave (contiguous 10-20 KiB windows),
// so HBM traffic is unchanged; R4 already showed scattered z beats staging.
// Deleting LDS removes all ds round-trips, the LDS residency cap, and the
// bank conflicts. Math is bit-identical to R3/R4 (same FP order everywhere).

#define HN 10
#define ND 40
#define HF 8
#define TPB 256

__global__ __launch_bounds__(TPB) void gnn_kernel(
    const float* __restrict__ x,          // [B, 40]
    const float* __restrict__ z,          // [B, 10, 8]
    const float* __restrict__ y,          // [B, 40]
    const float* __restrict__ enc_rel_w,  // [8, 1]
    const float* __restrict__ enc_rel_b,  // [8]
    const float* __restrict__ enc_root_w, // [8, 8]
    const float* __restrict__ pred_rel_w, // [8, 8]
    const float* __restrict__ pred_rel_b, // [8]
    const float* __restrict__ pred_root_w,// [8, 8]
    const float* __restrict__ dec_rel_w,  // [1, 8]
    const float* __restrict__ dec_rel_b,  // [1]
    const float* __restrict__ dec_root_w, // [1, 1]
    float* __restrict__ out,              // [B, 40]
    int B)
{
    const long long e = (long long)blockIdx.x * TPB + threadIdx.x;

    const float w = 0.8948393168143698f;  // exp(-(1/3)^2) as fp32

    // ---------- x: own row, 10 x global_load_dwordx4 ----------
    const float4* xr = (const float4*)(x + e * ND);
    float xv[ND];
    #pragma unroll
    for (int k = 0; k < 10; ++k) {
        float4 v = xr[k];
        xv[4*k+0] = v.x; xv[4*k+1] = v.y; xv[4*k+2] = v.z; xv[4*k+3] = v.w;
    }

    float agg[HN];
    agg[0] = xv[37] + xv[38] + xv[39] + xv[0] + xv[1] + xv[2];
    #pragma unroll
    for (int j = 1; j < HN; ++j)
        agg[j] = xv[4*j-3] + xv[4*j-2] + xv[4*j-1] + xv[4*j] + xv[4*j+1] + xv[4*j+2];

    // ---------- z: own 320 B row, registers only ----------
    const float4* zr = (const float4*)(z + e * (HN * HF));

    // encoder GraphConv row j from two z float4s (registers only)
    auto enc_row = [&](float4 v0, float4 v1, int j, float (&r)[HF]) {
        float zrow[HF] = {v0.x, v0.y, v0.z, v0.w, v1.x, v1.y, v1.z, v1.w};
        #pragma unroll
        for (int f = 0; f < HF; ++f) {
            float acc = agg[j] * enc_rel_w[f] + enc_rel_b[f];
            #pragma unroll
            for (int g = 0; g < HF; ++g)
                acc += zrow[g] * enc_root_w[f * HF + g];
            r[f] = fmaxf(acc, 0.0f);
        }
    };

    // predictor + decoder row-dot: s2 for center row rc with neighbors rm, rp
    auto emit = [&](const float (&rm)[HF], const float (&rc)[HF],
                    const float (&rp)[HF]) -> float {
        float a2[HF];
        #pragma unroll
        for (int f = 0; f < HF; ++f)
            a2[f] = rc[f] + w * (rm[f] + rp[f]);
        float s = 0.0f;
        #pragma unroll
        for (int f = 0; f < HF; ++f) {
            float acc = pred_rel_b[f];
            #pragma unroll
            for (int g = 0; g < HF; ++g)
                acc += a2[g] * pred_rel_w[f * HF + g];
            #pragma unroll
            for (int g = 0; g < HF; ++g)
                acc += rc[g] * pred_root_w[f * HF + g];
            s += fmaxf(acc, 0.0f) * dec_rel_w[f];
        }
        return s;
    };

    // nodes 0..4 (zA), then 5..9 (zB) — two landing waves to bound VGPRs
    float rA[5][HF], rB[5][HF];
    {
        float4 zA[10];
        #pragma unroll
        for (int k = 0; k < 10; ++k) zA[k] = zr[k];
        #pragma unroll
        for (int jj = 0; jj < 5; ++jj) enc_row(zA[2*jj], zA[2*jj+1], jj, rA[jj]);
    }
    {
        float4 zB[10];
        #pragma unroll
        for (int k = 0; k < 10; ++k) zB[k] = zr[10 + k];
        #pragma unroll
        for (int jj = 0; jj < 5; ++jj) enc_row(zB[2*jj], zB[2*jj+1], 5 + jj, rB[jj]);
    }

    // ---------- y: own row, issued before emits so it overlaps compute ----
    const float4* yr = (const float4*)(y + e * ND);
    float4 yv[10];
    #pragma unroll
    for (int k = 0; k < 10; ++k) yv[k] = yr[k];

    float s2[HN];
    s2[1] = emit(rA[0], rA[1], rA[2]);
    s2[2] = emit(rA[1], rA[2], rA[3]);
    s2[3] = emit(rA[2], rA[3], rA[4]);
    s2[4] = emit(rA[3], rA[4], rB[0]);
    s2[5] = emit(rA[4], rB[0], rB[1]);
    s2[6] = emit(rB[0], rB[1], rB[2]);
    s2[7] = emit(rB[1], rB[2], rB[3]);
    s2[8] = emit(rB[2], rB[3], rB[4]);
    s2[9] = emit(rB[3], rB[4], rA[0]);
    s2[0] = emit(rB[4], rA[0], rA[1]);

    // ---------- out: own row, 10 x global_store_dwordx4 ----------
    const float drb   = dec_rel_b[0];
    const float droot = dec_root_w[0];
    float4* og = (float4*)(out + e * ND);
    #pragma unroll
    for (int k = 0; k < 10; ++k) {
        const int k1 = (k + 1) % HN;
        const float pair = s2[k] + s2[k1] + drb;
        float4 o;
        o.x = (s2[k]  + drb) + yv[k].x * droot;
        o.y = pair           + yv[k].y * droot;
        o.z = pair           + yv[k].z * droot;
        o.w = (s2[k1] + drb) + yv[k].w * droot;
        og[k] = o;
    }
}

extern "C" void kernel_launch(void* const* d_in, const int* in_sizes, int n_in,
                              void* d_out, int out_size, void* d_ws, size_t ws_size,
                              hipStream_t stream) {
    const float* x          = (const float*)d_in[0];
    const float* z          = (const float*)d_in[1];
    const float* y          = (const float*)d_in[2];
    const float* enc_rel_w  = (const float*)d_in[3];
    const float* enc_rel_b  = (const float*)d_in[4];
    const float* enc_root_w = (const float*)d_in[5];
    const float* pred_rel_w = (const float*)d_in[6];
    const float* pred_rel_b = (const float*)d_in[7];
    const float* pred_root_w= (const float*)d_in[8];
    const float* dec_rel_w  = (const float*)d_in[9];
    const float* dec_rel_b  = (const float*)d_in[10];
    const float* dec_root_w = (const float*)d_in[11];
    float* out = (float*)d_out;

    const int B = in_sizes[0] / ND;       // 524288, divisible by TPB
    const int blocks = B / TPB;
    gnn_kernel<<<blocks, TPB, 0, stream>>>(
        x, z, y, enc_rel_w, enc_rel_b, enc_root_w,
        pred_rel_w, pred_rel_b, pred_root_w,
        dec_rel_w, dec_rel_b, dec_root_w, out, B);
}